// Round 5
// baseline (95.044 us; speedup 1.0000x reference)
//
#include <hip/hip_runtime.h>
#include <math.h>

#define TT 8192
#define FF 64

typedef float f32x2 __attribute__((ext_vector_type(2)));
typedef float f32x4 __attribute__((ext_vector_type(4)));

__device__ __forceinline__ float rcpf(float x) { return __builtin_amdgcn_rcpf(x); }

// ---- prep: softmax rows of W -> wsmT[j*64 + i] = softmax(W)[i][j] (f32, for s_load) ----
__global__ void prep_kernel(const float* __restrict__ W, float* __restrict__ wsmT) {
    const int lane = threadIdx.x;   // j
    const int wv   = threadIdx.y;   // 0..3
    for (int it = 0; it < 16; ++it) {
        const int r = wv * 16 + it; // i
        float v = W[r * 64 + lane];
        float m = v;
        #pragma unroll
        for (int off = 32; off >= 1; off >>= 1)
            m = fmaxf(m, __shfl_xor(m, off, 64));
        float e = __expf(v - m);
        float s = e;
        #pragma unroll
        for (int off = 32; off >= 1; off >>= 1)
            s += __shfl_xor(s, off, 64);
        wsmT[lane * 64 + r] = e * rcpf(s);
    }
}

// ---- kernel 1: FIR (memory term) + proj + global term -> memout, partial out ----
#define FTILE 32
#define FHALO 50
__global__ __launch_bounds__(256, 4)
void fir_kernel(const float* __restrict__ x, const float* __restrict__ PW,
                const float* __restrict__ pb, const float* __restrict__ kap,
                const float* __restrict__ coeffs,
                float* __restrict__ out, float* __restrict__ memout) {
    __shared__ float xs[(FTILE + FHALO) * 64];   // 20992 B
    __shared__ f32x4 pw_lds[64 * 16];            // 16384 B  (37376 total -> 4 blocks/CU)

    const int tid = threadIdx.x, lane = tid & 63, wv = tid >> 6;
    const int sw = ((int)blockIdx.x & 7) * 128 + ((int)blockIdx.x >> 3);  // XCD swizzle
    const int b  = sw >> 8;
    const int t0 = (sw & 255) * FTILE;
    const float* xb = x + (size_t)b * TT * FF;

    for (int i4 = tid; i4 < (FTILE + FHALO) * 16; i4 += 256) {
        const int e0 = i4 * 4, s = e0 >> 6, f = e0 & 63, t = t0 - FHALO + s;
        f32x4 v = {0.f, 0.f, 0.f, 0.f};
        if (t >= 0) v = *(const f32x4*)(xb + (size_t)t * 64 + f);
        *(f32x4*)(&xs[e0]) = v;
    }
    #pragma unroll
    for (int k = 0; k < 4; ++k) {   // stage PW swizzled (conflict-free readback)
        const int idx = tid + 256 * k, rw = idx >> 4, qw = idx & 15;
        pw_lds[rw * 16 + ((qw + rw) & 15)] = ((const f32x4*)PW)[idx];
    }
    __syncthreads();

    // pw row for this lane (output feature) into VGPRs
    float pwv[64];
    #pragma unroll
    for (int q = 0; q < 16; ++q) {
        const f32x4 v = pw_lds[lane * 16 + ((q + lane) & 15)];
        pwv[4*q] = v.x; pwv[4*q+1] = v.y; pwv[4*q+2] = v.z; pwv[4*q+3] = v.w;
    }

    const int base = wv * 8;
    float macc[8] = {0.f,0.f,0.f,0.f,0.f,0.f,0.f,0.f};
    #pragma unroll
    for (int s = 0; s < 58; ++s) {
        const float xv = xs[(base + s) * 64 + lane];
        #pragma unroll
        for (int r = 0; r < 8; ++r) {
            const int k = 50 + r - s;
            if (0 <= k && k <= 50) macc[r] = fmaf(coeffs[k], xv, macc[r]);
        }
    }

    const float kappa  = kap[0];
    const float inv1mr = rcpf(1.f - __expf(-kappa));
    const float pbias  = pb[lane];

    #pragma unroll
    for (int r = 0; r < 8; ++r) {
        const int trow = t0 + base + r;
        const float* xrow = xb + (size_t)trow * 64;   // uniform -> s_load broadcasts
        float pacc = 0.f;
        #pragma unroll
        for (int f = 0; f < 64; ++f)
            pacc = fmaf(xrow[f], pwv[f], pacc);
        const float ksum = (1.f - __expf(-kappa * (float)(trow + 1))) * inv1mr;
        const size_t o = (size_t)(b * TT + trow) * 64 + lane;
        memout[o] = macc[r];
        out[o] = fmaf(0.3f, macc[r], 0.3f * (pacc + pbias) * ksum);
    }
}

// ---- kernel 2: coupling, transposed (lane = row). out += 0.4 * c ----
#define MTILE 64
__global__ __launch_bounds__(1024, 8)
void coup_kernel(const float* __restrict__ x, const float* __restrict__ wsmT,
                 float* __restrict__ out) {
    __shared__ f32x2 tuT[64 * 64];   // {tanh, e^-|x|} per [feature][row]  32768 B
    __shared__ float cT[64 * 64];    // transposed result buffer           16384 B

    const int tid = threadIdx.x, lane = tid & 63, wv = tid >> 6;  // wv 0..15
    const int bid = (int)blockIdx.x;
    const int b   = bid >> 7;             // 512 blocks = 4 batch * 128 tiles
    const int t0  = (bid & 127) * MTILE;
    const float* xb = x + (size_t)b * TT * FF;

    // stage tuT: thread -> (row = tid>>4, 4 features)
    {
        const int row = tid >> 4, fq = tid & 15;
        const f32x4 xv = ((const f32x4*)(xb + (size_t)(t0 + row) * 64))[fq];
        #pragma unroll
        for (int q = 0; q < 4; ++q) {
            const float xi = (q == 0) ? xv.x : (q == 1) ? xv.y : (q == 2) ? xv.z : xv.w;
            const float E  = __expf(2.f * xi);
            f32x2 p;
            p.x = fmaf(-2.f, rcpf(E + 1.f), 1.f);   // tanh(xi)
            p.y = __expf(-fabsf(xi));               // e^{-|xi|}
            tuT[(fq * 4 + q) * 64 + row] = p;
        }
    }
    __syncthreads();

    const int i0 = wv * 4;
    f32x2 tiu[4], niu[4];
    #pragma unroll
    for (int i = 0; i < 4; ++i) {
        tiu[i] = tuT[(i0 + i) * 64 + lane];
        niu[i].x = -tiu[i].x;
        niu[i].y =  tiu[i].y;
    }

    float cacc[4] = {0.f, 0.f, 0.f, 0.f};
    const f32x4* w4 = (const f32x4*)wsmT;
    #pragma unroll 8
    for (int j = 0; j < 64; ++j) {
        const f32x2 tj = tuT[j * 64 + lane];    // per-lane ds_read_b64
        const f32x4 wj = w4[j * 16 + wv];       // uniform -> s_load_dwordx4
        #pragma unroll
        for (int i = 0; i < 4; ++i) {
            const float d1 = fmaf(niu[i].x, tj.x, 1.f);   // 1 - ti*tj
            const float d2 = fmaf(niu[i].y, tj.y, 1.f);   // 1 + ui*uj
            const float rr = rcpf(d1 * d2);
            const float num = tiu[i].x - tj.x;
            const float wij = (i == 0) ? wj.x : (i == 1) ? wj.y : (i == 2) ? wj.z : wj.w;
            cacc[i] = fmaf(num * wij, rr, cacc[i]);
        }
    }

    #pragma unroll
    for (int i = 0; i < 4; ++i)   // swizzled transpose store
        cT[(i0 + i) * 64 + ((lane + i0 + i) & 63)] = 0.4f * cacc[i];
    __syncthreads();

    {
        const int row = tid >> 4, iq = tid & 15;
        f32x4 c;
        c.x = cT[(iq*4+0) * 64 + ((row + iq*4+0) & 63)];
        c.y = cT[(iq*4+1) * 64 + ((row + iq*4+1) & 63)];
        c.z = cT[(iq*4+2) * 64 + ((row + iq*4+2) & 63)];
        c.w = cT[(iq*4+3) * 64 + ((row + iq*4+3) & 63)];
        f32x4* op = (f32x4*)(out + (size_t)(b * TT + t0 + row) * 64) + iq;
        f32x4 o = *op;
        o.x += c.x; o.y += c.y; o.z += c.z; o.w += c.w;
        *op = o;
    }
}

extern "C" void kernel_launch(void* const* d_in, const int* in_sizes, int n_in,
                              void* d_out, int out_size, void* d_ws, size_t ws_size,
                              hipStream_t stream) {
    const float* x   = (const float*)d_in[0];
    const float* W   = (const float*)d_in[1];
    const float* PW  = (const float*)d_in[2];
    const float* pb  = (const float*)d_in[3];
    const float* kap = (const float*)d_in[4];
    const float* cf  = (const float*)d_in[5];

    float* out    = (float*)d_out;
    float* memout = out + (size_t)4 * TT * FF;
    float* wsmT   = (float*)d_ws;   // 16 KB

    hipLaunchKernelGGL(prep_kernel, dim3(1), dim3(64, 4), 0, stream, W, wsmT);
    hipLaunchKernelGGL(fir_kernel, dim3(4 * (TT / FTILE)), dim3(256), 0, stream,
                       x, PW, pb, kap, cf, out, memout);
    hipLaunchKernelGGL(coup_kernel, dim3(4 * (TT / MTILE)), dim3(1024), 0, stream,
                       x, wsmT, out);
}

// Round 6
// 55.859 us; speedup vs baseline: 1.7015x; 1.7015x over previous
//
#include <hip/hip_runtime.h>
#include <math.h>

#define TT 8192
#define FF 64

typedef float f32x2 __attribute__((ext_vector_type(2)));
typedef float f32x4 __attribute__((ext_vector_type(4)));

__device__ __forceinline__ float rcpf(float x) { return __builtin_amdgcn_rcpf(x); }

// ---- prep: wsmT[j*64+i] = softmax(W)[i][j]; pwT[j*64+i] = PW[i*64+j] ----
__global__ void prep_kernel(const float* __restrict__ W, const float* __restrict__ PW,
                            float* __restrict__ wsmT, float* __restrict__ pwT) {
    const int lane = threadIdx.x;   // j
    const int wv   = threadIdx.y;   // 0..3
    for (int it = 0; it < 16; ++it) {
        const int r = wv * 16 + it; // i
        float v = W[r * 64 + lane];
        float m = v;
        #pragma unroll
        for (int off = 32; off >= 1; off >>= 1)
            m = fmaxf(m, __shfl_xor(m, off, 64));
        float e = __expf(v - m);
        float s = e;
        #pragma unroll
        for (int off = 32; off >= 1; off >>= 1)
            s += __shfl_xor(s, off, 64);
        wsmT[lane * 64 + r] = e * rcpf(s);
        pwT[lane * 64 + r]  = PW[r * 64 + lane];
    }
}

// ---- kernel 1: pure FIR -> memout ----
#define FTILE 64
#define FHALO 50
__global__ __launch_bounds__(512, 8)
void fir_kernel(const float* __restrict__ x, const float* __restrict__ coeffs,
                float* __restrict__ memout) {
    __shared__ float xs[(FTILE + FHALO) * 64];   // 29184 B -> 4 blocks/CU (32 waves)

    const int tid = threadIdx.x, lane = tid & 63, wv = tid >> 6;   // wv 0..7
    const int sw = ((int)blockIdx.x & 7) * 64 + ((int)blockIdx.x >> 3);  // XCD swizzle
    const int b  = sw >> 7;
    const int t0 = (sw & 127) * FTILE;
    const float* xb = x + (size_t)b * TT * FF;

    for (int i4 = tid; i4 < (FTILE + FHALO) * 16; i4 += 512) {
        const int e0 = i4 * 4, s = i4 >> 4, f = e0 & 63, t = t0 - FHALO + s;
        f32x4 v = {0.f, 0.f, 0.f, 0.f};
        if (t >= 0) v = *(const f32x4*)(xb + (size_t)t * 64 + f);
        *(f32x4*)(&xs[e0]) = v;
    }
    __syncthreads();

    const int base = wv * 8;
    float macc[8] = {0.f,0.f,0.f,0.f,0.f,0.f,0.f,0.f};
    #pragma unroll
    for (int s = 0; s < 58; ++s) {
        const float xv = xs[(base + s) * 64 + lane];
        #pragma unroll
        for (int r = 0; r < 8; ++r) {
            const int k = 50 + r - s;
            if (0 <= k && k <= 50) macc[r] = fmaf(coeffs[k], xv, macc[r]);
        }
    }
    #pragma unroll
    for (int r = 0; r < 8; ++r)
        memout[(size_t)(b * TT + t0 + base + r) * 64 + lane] = macc[r];
}

// ---- kernel 2: coupling + proj + global term -> out (single write) ----
__global__ __launch_bounds__(1024, 8)
void coup_kernel(const float* __restrict__ x, const float* __restrict__ wsmT,
                 const float* __restrict__ pwT, const float* __restrict__ pb,
                 const float* __restrict__ kap, const float* __restrict__ memout,
                 float* __restrict__ out) {
    __shared__ f32x2 tuT[64 * 64];   // {tanh, e^-|x|}[feature][row]  32768 B
    __shared__ float xT[64 * 65];    // x[feature][row], padded       16640 B
    __shared__ float cT[64 * 64];    //                               16384 B (65792 total)

    const int tid = threadIdx.x, lane = tid & 63, wv = tid >> 6;  // wv 0..15
    const int sw = ((int)blockIdx.x & 7) * 64 + ((int)blockIdx.x >> 3);  // same swizzle as fir
    const int b  = sw >> 7;
    const int t0 = (sw & 127) * 64;
    const float* xb = x + (size_t)b * TT * FF;

    // stage xT (transposed), pad-65 => ~2-way banks
    {
        const int row = tid >> 4, fq = tid & 15;
        const f32x4 xv = ((const f32x4*)(xb + (size_t)(t0 + row) * 64))[fq];
        xT[(fq*4+0) * 65 + row] = xv.x;
        xT[(fq*4+1) * 65 + row] = xv.y;
        xT[(fq*4+2) * 65 + row] = xv.z;
        xT[(fq*4+3) * 65 + row] = xv.w;
    }
    __syncthreads();

    // tuT: wave wv handles features 4wv..4wv+3, lane = row
    #pragma unroll
    for (int q = 0; q < 4; ++q) {
        const int f = wv * 4 + q;
        const float xi = xT[f * 65 + lane];
        const float E  = __expf(2.f * xi);
        f32x2 p;
        p.x = fmaf(-2.f, rcpf(E + 1.f), 1.f);   // tanh
        p.y = __expf(-fabsf(xi));               // e^-|x|
        tuT[f * 64 + lane] = p;
    }
    __syncthreads();

    const int i0 = wv * 4;
    f32x2 tiu[4];
    #pragma unroll
    for (int i = 0; i < 4; ++i) tiu[i] = tuT[(i0 + i) * 64 + lane];

    float cacc[4] = {0.f,0.f,0.f,0.f};
    float pacc[4] = {0.f,0.f,0.f,0.f};
    const f32x4* w4 = (const f32x4*)wsmT;
    const f32x4* p4 = (const f32x4*)pwT;
    #pragma unroll 4
    for (int j = 0; j < 64; ++j) {
        const f32x2 tj = tuT[j * 64 + lane];    // per-lane b64, 2-way free
        const float xj = xT[j * 65 + lane];     // per-lane b32, conflict-free
        const f32x4 wj = w4[j * 16 + wv];       // uniform -> s_load_dwordx4
        const f32x4 pj = p4[j * 16 + wv];       // uniform -> s_load_dwordx4
        #pragma unroll
        for (int i = 0; i < 4; ++i) {
            const float d1 = fmaf(-tiu[i].x, tj.x, 1.f);   // 1 - ti*tj
            const float d2 = fmaf( tiu[i].y, tj.y, 1.f);   // 1 + ui*uj
            const float rr = rcpf(d1 * d2);
            const float num = tiu[i].x - tj.x;
            const float wij = (i==0)?wj.x:(i==1)?wj.y:(i==2)?wj.z:wj.w;
            const float pij = (i==0)?pj.x:(i==1)?pj.y:(i==2)?pj.z:pj.w;
            cacc[i] = fmaf(num * wij, rr, cacc[i]);
            pacc[i] = fmaf(xj, pij, pacc[i]);
        }
    }

    const float kappa  = kap[0];
    const float ksum   = (1.f - __expf(-kappa * (float)(t0 + lane + 1))) *
                         rcpf(1.f - __expf(-kappa));      // lane = row
    #pragma unroll
    for (int i = 0; i < 4; ++i) {
        const float val = fmaf(0.4f, cacc[i], 0.3f * (pacc[i] + pb[i0 + i]) * ksum);
        cT[(i0 + i) * 64 + ((lane + i0 + i) & 63)] = val;  // swizzled transpose store
    }
    __syncthreads();

    {
        const int row = tid >> 4, iq = tid & 15;
        f32x4 c;
        c.x = cT[(iq*4+0) * 64 + ((row + iq*4+0) & 63)];
        c.y = cT[(iq*4+1) * 64 + ((row + iq*4+1) & 63)];
        c.z = cT[(iq*4+2) * 64 + ((row + iq*4+2) & 63)];
        c.w = cT[(iq*4+3) * 64 + ((row + iq*4+3) & 63)];
        const size_t ro = (size_t)(b * TT + t0 + row) * 64;
        const f32x4 m4 = *((const f32x4*)(memout + ro) + iq);
        f32x4 o;
        o.x = fmaf(0.3f, m4.x, c.x);
        o.y = fmaf(0.3f, m4.y, c.y);
        o.z = fmaf(0.3f, m4.z, c.z);
        o.w = fmaf(0.3f, m4.w, c.w);
        *((f32x4*)(out + ro) + iq) = o;
    }
}

extern "C" void kernel_launch(void* const* d_in, const int* in_sizes, int n_in,
                              void* d_out, int out_size, void* d_ws, size_t ws_size,
                              hipStream_t stream) {
    const float* x   = (const float*)d_in[0];
    const float* W   = (const float*)d_in[1];
    const float* PW  = (const float*)d_in[2];
    const float* pb  = (const float*)d_in[3];
    const float* kap = (const float*)d_in[4];
    const float* cf  = (const float*)d_in[5];

    float* out    = (float*)d_out;
    float* memout = out + (size_t)4 * TT * FF;

    float* wsmT = (float*)d_ws;          // 16 KB
    float* pwT  = wsmT + 64 * 64;        // 16 KB

    hipLaunchKernelGGL(prep_kernel, dim3(1), dim3(64, 4), 0, stream, W, PW, wsmT, pwT);
    hipLaunchKernelGGL(fir_kernel, dim3(4 * (TT / FTILE)), dim3(512), 0, stream,
                       x, cf, memout);
    hipLaunchKernelGGL(coup_kernel, dim3(4 * (TT / 64)), dim3(1024), 0, stream,
                       x, wsmT, pwT, pb, kap, memout, out);
}

// Round 7
// 49.198 us; speedup vs baseline: 1.9319x; 1.1354x over previous
//
#include <hip/hip_runtime.h>
#include <math.h>

#define TT 8192
#define FF 64

typedef float f32x4 __attribute__((ext_vector_type(4)));

__device__ __forceinline__ float rcpf(float x) { return __builtin_amdgcn_rcpf(x); }

// ---- prep: wsmT[j*64+i] = softmax(W)[i][j] ----
__global__ void prep_kernel(const float* __restrict__ W, float* __restrict__ wsmT) {
    const int lane = threadIdx.x;   // j
    const int wv   = threadIdx.y;   // 0..3
    for (int it = 0; it < 16; ++it) {
        const int r = wv * 16 + it; // i
        float v = W[r * 64 + lane];
        float m = v;
        #pragma unroll
        for (int off = 32; off >= 1; off >>= 1)
            m = fmaxf(m, __shfl_xor(m, off, 64));
        float e = __expf(v - m);
        float s = e;
        #pragma unroll
        for (int off = 32; off >= 1; off >>= 1)
            s += __shfl_xor(s, off, 64);
        wsmT[lane * 64 + r] = e * rcpf(s);
    }
}

// ---- kernel 1: FIR + proj + global term -> memout, out_partial ----
#define FTILE 32
#define FHALO 50
__global__ __launch_bounds__(512, 8)
void fir_kernel(const float* __restrict__ x, const float* __restrict__ PW,
                const float* __restrict__ pb, const float* __restrict__ kap,
                const float* __restrict__ coeffs,
                float* __restrict__ out, float* __restrict__ memout) {
    __shared__ float xs[(FTILE + FHALO) * 64];   // 20992 B
    __shared__ float pwS[64 * 64];               // 16384 B (37376 -> 4 blocks/CU)

    const int tid = threadIdx.x, lane = tid & 63, wv = tid >> 6;   // wv 0..7
    const int sw = ((int)blockIdx.x & 7) * 128 + ((int)blockIdx.x >> 3);  // XCD swizzle
    const int b  = sw >> 8;
    const int t0 = (sw & 255) * FTILE;
    const float* xb = x + (size_t)b * TT * FF;

    // stage xs rows [t0-50, t0+32), zero-pad t<0
    for (int i4 = tid; i4 < (FTILE + FHALO) * 16; i4 += 512) {
        const int s = i4 >> 4, f4 = i4 & 15, t = t0 - FHALO + s;
        f32x4 v = {0.f, 0.f, 0.f, 0.f};
        if (t >= 0) v = *(const f32x4*)(xb + (size_t)t * 64 + f4 * 4);
        *(f32x4*)(&xs[s * 64 + f4 * 4]) = v;
    }
    // stage PW quads, XOR-swizzled: row i quad q at i*64 + ((q^(i&15))<<2)
    #pragma unroll
    for (int k = 0; k < 2; ++k) {
        const int g = tid + 512 * k, i = g >> 4, q = g & 15;
        *(f32x4*)(&pwS[i * 64 + ((q ^ (i & 15)) << 2)]) = ((const f32x4*)PW)[g];
    }
    __syncthreads();

    // ---- FIR: wave owns rows 4wv..4wv+3 (xs row lt+50) ----
    float macc[4] = {0.f, 0.f, 0.f, 0.f};
    #pragma unroll
    for (int s = 0; s < 54; ++s) {
        const float xv = xs[(4 * wv + s) * 64 + lane];
        #pragma unroll
        for (int r = 0; r < 4; ++r) {
            const int k = r + 50 - s;
            if (0 <= k && k <= 50) macc[r] = fmaf(coeffs[k], xv, macc[r]);
        }
    }

    // ---- proj: lane = output feature i; x rows broadcast via uniform b128 ----
    float pacc[4] = {0.f, 0.f, 0.f, 0.f};
    #pragma unroll
    for (int q = 0; q < 16; ++q) {
        const f32x4 pw4 = *(const f32x4*)(&pwS[lane * 64 + ((q ^ (lane & 15)) << 2)]);
        #pragma unroll
        for (int r = 0; r < 4; ++r) {
            const f32x4 x4 = *(const f32x4*)(&xs[(4 * wv + r + FHALO) * 64 + q * 4]);
            pacc[r] = fmaf(x4.x, pw4.x, pacc[r]);
            pacc[r] = fmaf(x4.y, pw4.y, pacc[r]);
            pacc[r] = fmaf(x4.z, pw4.z, pacc[r]);
            pacc[r] = fmaf(x4.w, pw4.w, pacc[r]);
        }
    }

    const float kappa  = kap[0];
    const float inv1mr = rcpf(1.f - __expf(-kappa));
    const float pbias  = pb[lane];

    #pragma unroll
    for (int r = 0; r < 4; ++r) {
        const int trow = t0 + 4 * wv + r;
        const float ksum = (1.f - __expf(-kappa * (float)(trow + 1))) * inv1mr;
        const size_t o = (size_t)(b * TT + trow) * 64 + lane;
        memout[o] = macc[r];
        out[o] = fmaf(0.3f, macc[r], 0.3f * (pacc[r] + pbias) * ksum);
    }
}

// ---- kernel 2: coupling (transposed, lane=row); out += 0.4*c ----
__global__ __launch_bounds__(1024, 8)
void coup_kernel(const float* __restrict__ x, const float* __restrict__ wsmT,
                 float* __restrict__ out) {
    __shared__ float tS[64 * 65];   // tanh[f][row], pad-65   16640 B
    __shared__ float uS[64 * 65];   // e^-|x|[f][row]         16640 B
    __shared__ float wS[64 * 64];   // w[j][i]                16384 B  (49664 total)

    const int tid = threadIdx.x, lane = tid & 63, wv = tid >> 6;  // wv 0..15
    const int sw = ((int)blockIdx.x & 7) * 64 + ((int)blockIdx.x >> 3);
    const int b  = sw >> 7;
    const int t0 = (sw & 127) * 64;
    const float* xb = x + (size_t)b * TT * FF;

    // stage wS (one f32x4 per thread)
    ((f32x4*)wS)[tid] = ((const f32x4*)wsmT)[tid];
    // stage tS/uS: thread (row=tid>>4, fq=tid&15) computes 4 features
    {
        const int row = tid >> 4, fq = tid & 15;
        const f32x4 xv = ((const f32x4*)(xb + (size_t)(t0 + row) * 64))[fq];
        #pragma unroll
        for (int q = 0; q < 4; ++q) {
            const float xi = (q == 0) ? xv.x : (q == 1) ? xv.y : (q == 2) ? xv.z : xv.w;
            const float E  = __expf(2.f * xi);
            const int f = fq * 4 + q;
            tS[f * 65 + row] = fmaf(-2.f, rcpf(E + 1.f), 1.f);   // tanh
            uS[f * 65 + row] = __expf(-fabsf(xi));               // e^-|x|
        }
    }
    __syncthreads();

    const int i0 = wv * 4;
    float ti[4], ui[4];
    #pragma unroll
    for (int i = 0; i < 4; ++i) {
        ti[i] = tS[(i0 + i) * 65 + lane];
        ui[i] = uS[(i0 + i) * 65 + lane];
    }

    float cacc[4] = {0.f, 0.f, 0.f, 0.f};
    #pragma unroll 8
    for (int j = 0; j < 64; ++j) {
        const float tj = tS[j * 65 + lane];                 // 2-way free, imm offset
        const float uj = uS[j * 65 + lane];
        const f32x4 w4 = *(const f32x4*)(&wS[j * 64 + i0]); // uniform broadcast b128
        #pragma unroll
        for (int i = 0; i < 4; ++i) {
            const float d1 = fmaf(-ti[i], tj, 1.f);   // 1 - ti*tj
            const float d2 = fmaf( ui[i], uj, 1.f);   // 1 + ui*uj
            const float rr = rcpf(d1 * d2);
            const float wij = (i == 0) ? w4.x : (i == 1) ? w4.y : (i == 2) ? w4.z : w4.w;
            cacc[i] = fmaf((ti[i] - tj) * wij, rr, cacc[i]);
        }
    }

    __syncthreads();   // tS dead; reuse as transpose buffer
    #pragma unroll
    for (int i = 0; i < 4; ++i)
        tS[(i0 + i) * 65 + lane] = cacc[i];
    __syncthreads();

    {
        const int row = tid >> 4, iq = tid & 15;
        f32x4 c;
        c.x = tS[(iq * 4 + 0) * 65 + row];
        c.y = tS[(iq * 4 + 1) * 65 + row];
        c.z = tS[(iq * 4 + 2) * 65 + row];
        c.w = tS[(iq * 4 + 3) * 65 + row];
        const size_t ro = (size_t)(b * TT + t0 + row) * 64;
        f32x4 g = *((const f32x4*)(out + ro) + iq);   // partial from fir_kernel
        f32x4 o;
        o.x = fmaf(0.4f, c.x, g.x);
        o.y = fmaf(0.4f, c.y, g.y);
        o.z = fmaf(0.4f, c.z, g.z);
        o.w = fmaf(0.4f, c.w, g.w);
        *((f32x4*)(out + ro) + iq) = o;
    }
}

extern "C" void kernel_launch(void* const* d_in, const int* in_sizes, int n_in,
                              void* d_out, int out_size, void* d_ws, size_t ws_size,
                              hipStream_t stream) {
    const float* x   = (const float*)d_in[0];
    const float* W   = (const float*)d_in[1];
    const float* PW  = (const float*)d_in[2];
    const float* pb  = (const float*)d_in[3];
    const float* kap = (const float*)d_in[4];
    const float* cf  = (const float*)d_in[5];

    float* out    = (float*)d_out;
    float* memout = out + (size_t)4 * TT * FF;
    float* wsmT   = (float*)d_ws;   // 16 KB

    hipLaunchKernelGGL(prep_kernel, dim3(1), dim3(64, 4), 0, stream, W, wsmT);
    hipLaunchKernelGGL(fir_kernel, dim3(4 * (TT / FTILE)), dim3(512), 0, stream,
                       x, PW, pb, kap, cf, out, memout);
    hipLaunchKernelGGL(coup_kernel, dim3(4 * (TT / 64)), dim3(1024), 0, stream,
                       x, wsmT, out);
}